// Round 2
// baseline (629.463 us; speedup 1.0000x reference)
//
#include <hip/hip_runtime.h>
#include <hip/hip_bf16.h>

typedef __attribute__((ext_vector_type(8))) short bf16x8;
typedef __attribute__((ext_vector_type(4))) float f32x4;

#define DH 128
#define DOUT 64

static __device__ __forceinline__ unsigned short f2bf(float f) {
    __hip_bfloat16 h = __float2bfloat16(f);
    return *(unsigned short*)&h;
}

// ---------------- CSR build ----------------

__global__ void zero_i32(int* __restrict__ p, int n) {
    int i = blockIdx.x * blockDim.x + threadIdx.x;
    if (i < n) p[i] = 0;
}

__global__ void hist_kernel(const int* __restrict__ dst, int* __restrict__ cnt,
                            int E, int n) {
    int e = blockIdx.x * blockDim.x + threadIdx.x;
    if (e < E) {
        int d = dst[e];
        if ((unsigned)d < (unsigned)n) atomicAdd(&cnt[d], 1);
    }
}

__global__ void scan1_kernel(const int* __restrict__ cnt, int* __restrict__ row_ptr,
                             int* __restrict__ bsum, int n) {
    __shared__ int s[256];
    int tid = threadIdx.x;
    int i = blockIdx.x * 256 + tid;
    int v = (i < n) ? cnt[i] : 0;
    s[tid] = v;
    __syncthreads();
    for (int off = 1; off < 256; off <<= 1) {
        int t = (tid >= off) ? s[tid - off] : 0;
        __syncthreads();
        s[tid] += t;
        __syncthreads();
    }
    if (i < n) row_ptr[i] = s[tid] - v;           // exclusive within block
    if (tid == 255) bsum[blockIdx.x] = s[255];    // block total
}

__global__ void scan2_kernel(int* __restrict__ bsum, int nb) {
    __shared__ int s[256];
    int tid = threadIdx.x;
    int v = (tid < nb) ? bsum[tid] : 0;
    s[tid] = v;
    __syncthreads();
    for (int off = 1; off < 256; off <<= 1) {
        int t = (tid >= off) ? s[tid - off] : 0;
        __syncthreads();
        s[tid] += t;
        __syncthreads();
    }
    if (tid < nb) bsum[tid] = s[tid] - v;         // exclusive block offsets
}

__global__ void scan3_kernel(int* __restrict__ row_ptr, const int* __restrict__ bsum,
                             int* __restrict__ cursor, int n, int E) {
    int i = blockIdx.x * 256 + threadIdx.x;
    if (i < n) {
        int v = row_ptr[i] + bsum[blockIdx.x];
        row_ptr[i] = v;
        cursor[i] = v;
    }
    if (i == 0) row_ptr[n] = E;
}

__global__ void fill_kernel(const int* __restrict__ src, const int* __restrict__ dst,
                            int* __restrict__ cursor, int* __restrict__ esrc,
                            int E, int n) {
    int e = blockIdx.x * blockDim.x + threadIdx.x;
    if (e < E) {
        int d = dst[e];
        if ((unsigned)d < (unsigned)n) {
            int p = atomicAdd(&cursor[d], 1);
            esrc[p] = src[e];
        }
    }
}

// ---------------- aggregation: z[i] = h[i] + sum_{e: dst=i} h[src_e] ----------------
// fp32 in / fp32 out. One wave per node, lane handles 2 features (float2).

__global__ void agg_kernel(const float* __restrict__ h,
                           const int* __restrict__ row_ptr,
                           const int* __restrict__ esrc,
                           float* __restrict__ z, int n) {
    int gid = blockIdx.x * blockDim.x + threadIdx.x;
    int node = gid >> 6;
    int lane = gid & 63;
    if (node >= n) return;
    const float2* h2 = (const float2*)h;
    float2 acc = h2[(size_t)node * 64 + lane];
    int b = row_ptr[node], e = row_ptr[node + 1];
    for (int j = b; j < e; ++j) {
        int s = esrc[j];
        float2 v = h2[(size_t)s * 64 + lane];
        acc.x += v.x;
        acc.y += v.y;
    }
    ((float2*)z)[(size_t)node * 64 + lane] = acc;
}

// ---------------- GEMM: C[M,NC] = act(A[M,128] @ W[128,NC] + b) ----------------
// fp32 storage, bf16 MFMA compute (convert during LDS staging), fp32 accumulate.
// MFMA 16x16x32 bf16. Block = 256 threads = 4 waves, 64-row M tile, full K=128.
// W staged transposed in LDS so the B-fragment read is a contiguous 16B ds_read.

template <int NC, bool RELU>
__launch_bounds__(256)
__global__ void gemm_kernel(const float* __restrict__ A,
                            const float* __restrict__ W,
                            const float* __restrict__ bias,
                            float* __restrict__ C, int M) {
    constexpr int K = 128;
    constexpr int MT = 64;
    constexpr int LDA = K + 8;  // pad to break bank-conflict stride
    __shared__ __align__(16) unsigned short As[MT][LDA];
    __shared__ __align__(16) unsigned short Wt[NC][LDA];

    int tid = threadIdx.x;
    int wave = tid >> 6;
    int lane = tid & 63;
    int row0 = blockIdx.x * MT;

    // stage A tile: 64 rows x 128 fp32 -> bf16, float4 loads
    for (int c = tid; c < MT * (K / 4); c += 256) {
        int r = c >> 5, ch = c & 31;
        float4 val = make_float4(0.f, 0.f, 0.f, 0.f);
        int grow = row0 + r;
        if (grow < M) val = *(const float4*)(A + (size_t)grow * K + ch * 4);
        ushort4 bv;
        bv.x = f2bf(val.x); bv.y = f2bf(val.y);
        bv.z = f2bf(val.z); bv.w = f2bf(val.w);
        *(ushort4*)(&As[r][ch * 4]) = bv;
    }
    // stage W transposed: Wt[n][k] = bf16(W[k*NC + n])
    for (int c = tid; c < K * NC; c += 256) {
        int k = c / NC, nn = c % NC;
        Wt[nn][k] = f2bf(W[c]);
    }
    __syncthreads();

    int quad = lane >> 4;     // 0..3
    int l16 = lane & 15;
    int arow = wave * 16 + l16;

#pragma unroll
    for (int nt = 0; nt < NC / 16; ++nt) {
        int ncol = nt * 16 + l16;
        f32x4 acc = {0.f, 0.f, 0.f, 0.f};
#pragma unroll
        for (int kt = 0; kt < 4; ++kt) {
            int koff = kt * 32 + quad * 8;
            bf16x8 a = *(const bf16x8*)(&As[arow][koff]);
            bf16x8 b = *(const bf16x8*)(&Wt[ncol][koff]);
            acc = __builtin_amdgcn_mfma_f32_16x16x32_bf16(a, b, acc, 0, 0, 0);
        }
        float bs = bias[ncol];
#pragma unroll
        for (int r = 0; r < 4; ++r) {
            int grow = row0 + wave * 16 + quad * 4 + r;
            if (grow < M) {
                float v = acc[r] + bs;
                if (RELU && v < 0.f) v = 0.f;
                C[(size_t)grow * NC + ncol] = v;
            }
        }
    }
}

// ---------------- launch ----------------

extern "C" void kernel_launch(void* const* d_in, const int* in_sizes, int n_in,
                              void* d_out, int out_size, void* d_ws, size_t ws_size,
                              hipStream_t stream) {
    const float* x = (const float*)d_in[0];
    const int* ei = (const int*)d_in[1];
    int N = in_sizes[0] / DH;
    int E = in_sizes[1] / 2;
    const int* src = ei;
    const int* dstv = ei + E;

    char* ws = (char*)d_ws;
    size_t off = 0;
    auto alloc = [&](size_t bytes) -> void* {
        void* p = ws + off;
        off += (bytes + 255) & ~(size_t)255;
        return p;
    };
    float* z    = (float*)alloc((size_t)N * DH * 4);
    float* t    = (float*)alloc((size_t)N * DH * 4);
    float* hbuf = (float*)alloc((size_t)N * DH * 4);
    int* cnt     = (int*)alloc((size_t)N * 4);
    int* row_ptr = (int*)alloc((size_t)(N + 1) * 4);
    int* cursor  = (int*)alloc((size_t)N * 4);
    int* bsum    = (int*)alloc(256 * 4);
    int* esrc    = (int*)alloc((size_t)E * 4);

    int nb = (N + 255) / 256;
    int eb = (E + 255) / 256;
    zero_i32<<<nb, 256, 0, stream>>>(cnt, N);
    hist_kernel<<<eb, 256, 0, stream>>>(dstv, cnt, E, N);
    scan1_kernel<<<nb, 256, 0, stream>>>(cnt, row_ptr, bsum, N);
    scan2_kernel<<<1, 256, 0, stream>>>(bsum, nb);
    scan3_kernel<<<nb, 256, 0, stream>>>(row_ptr, bsum, cursor, N, E);
    fill_kernel<<<eb, 256, 0, stream>>>(src, dstv, cursor, esrc, E, N);

    int ab = (N * 64 + 255) / 256;  // one wave per node
    int gb = (N + 63) / 64;         // 64-row tiles

    const float* c1w1 = (const float*)d_in[2];
    const float* c1b1 = (const float*)d_in[3];
    const float* c1w2 = (const float*)d_in[4];
    const float* c1b2 = (const float*)d_in[5];
    const float* c2w1 = (const float*)d_in[6];
    const float* c2b1 = (const float*)d_in[7];
    const float* c2w2 = (const float*)d_in[8];
    const float* c2b2 = (const float*)d_in[9];
    const float* c3w1 = (const float*)d_in[10];
    const float* c3b1 = (const float*)d_in[11];
    const float* c3w2 = (const float*)d_in[12];
    const float* c3b2 = (const float*)d_in[13];
    const float* l1w  = (const float*)d_in[14];
    const float* l1b  = (const float*)d_in[15];
    const float* l2w  = (const float*)d_in[16];
    const float* l2b  = (const float*)d_in[17];

    // conv1
    agg_kernel<<<ab, 256, 0, stream>>>(x, row_ptr, esrc, z, N);
    gemm_kernel<128, true><<<gb, 256, 0, stream>>>(z, c1w1, c1b1, t, N);
    gemm_kernel<128, true><<<gb, 256, 0, stream>>>(t, c1w2, c1b2, hbuf, N);
    // (outer relu after conv1 is a no-op: hbuf already relu'd)
    // conv2
    agg_kernel<<<ab, 256, 0, stream>>>(hbuf, row_ptr, esrc, z, N);
    gemm_kernel<128, true><<<gb, 256, 0, stream>>>(z, c2w1, c2b1, t, N);
    gemm_kernel<128, true><<<gb, 256, 0, stream>>>(t, c2w2, c2b2, hbuf, N);
    // conv3
    agg_kernel<<<ab, 256, 0, stream>>>(hbuf, row_ptr, esrc, z, N);
    gemm_kernel<128, true><<<gb, 256, 0, stream>>>(z, c3w1, c3b1, t, N);
    gemm_kernel<128, true><<<gb, 256, 0, stream>>>(t, c3w2, c3b2, hbuf, N);
    // head
    gemm_kernel<128, true><<<gb, 256, 0, stream>>>(hbuf, l1w, l1b, t, N);
    gemm_kernel<64, false><<<gb, 256, 0, stream>>>(t, l2w, l2b,
                                                   (float*)d_out, N);
}

// Round 3
// 579.789 us; speedup vs baseline: 1.0857x; 1.0857x over previous
//
#include <hip/hip_runtime.h>
#include <hip/hip_bf16.h>

typedef __attribute__((ext_vector_type(8))) short bf16x8;
typedef __attribute__((ext_vector_type(4))) float f32x4;

#define DH 128
#define DOUT 64

static __device__ __forceinline__ unsigned short f2bf(float f) {
    __hip_bfloat16 h = __float2bfloat16(f);
    return *(unsigned short*)&h;
}

// ---------------- CSR build ----------------

__global__ void zero_i32(int* __restrict__ p, int n) {
    int i = blockIdx.x * blockDim.x + threadIdx.x;
    if (i < n) p[i] = 0;
}

__global__ void hist_kernel(const int* __restrict__ dst, int* __restrict__ cnt,
                            int E, int n) {
    int e = blockIdx.x * blockDim.x + threadIdx.x;
    if (e < E) {
        int d = dst[e];
        if ((unsigned)d < (unsigned)n) atomicAdd(&cnt[d], 1);
    }
}

__global__ void scan1_kernel(const int* __restrict__ cnt, int* __restrict__ row_ptr,
                             int* __restrict__ bsum, int n) {
    __shared__ int s[256];
    int tid = threadIdx.x;
    int i = blockIdx.x * 256 + tid;
    int v = (i < n) ? cnt[i] : 0;
    s[tid] = v;
    __syncthreads();
    for (int off = 1; off < 256; off <<= 1) {
        int t = (tid >= off) ? s[tid - off] : 0;
        __syncthreads();
        s[tid] += t;
        __syncthreads();
    }
    if (i < n) row_ptr[i] = s[tid] - v;
    if (tid == 255) bsum[blockIdx.x] = s[255];
}

__global__ void scan2_kernel(int* __restrict__ bsum, int nb) {
    __shared__ int s[256];
    int tid = threadIdx.x;
    int v = (tid < nb) ? bsum[tid] : 0;
    s[tid] = v;
    __syncthreads();
    for (int off = 1; off < 256; off <<= 1) {
        int t = (tid >= off) ? s[tid - off] : 0;
        __syncthreads();
        s[tid] += t;
        __syncthreads();
    }
    if (tid < nb) bsum[tid] = s[tid] - v;
}

__global__ void scan3_kernel(int* __restrict__ row_ptr, const int* __restrict__ bsum,
                             int* __restrict__ cursor, int n, int E) {
    int i = blockIdx.x * 256 + threadIdx.x;
    if (i < n) {
        int v = row_ptr[i] + bsum[blockIdx.x];
        row_ptr[i] = v;
        cursor[i] = v;
    }
    if (i == 0) row_ptr[n] = E;
}

__global__ void fill_kernel(const int* __restrict__ src, const int* __restrict__ dst,
                            int* __restrict__ cursor, int* __restrict__ esrc,
                            int E, int n) {
    int e = blockIdx.x * blockDim.x + threadIdx.x;
    if (e < E) {
        int d = dst[e];
        if ((unsigned)d < (unsigned)n) {
            int p = atomicAdd(&cursor[d], 1);
            esrc[p] = src[e];
        }
    }
}

// ---------------- fused layer: [optional agg] -> GEMM1(relu) -> GEMM2(opt relu) ----------------
// Block = 256 threads (4 waves), 64-row M tile, K=128 full.
// LDS: As (A tile / Z intermediate, bf16) + Wt (W transposed, bf16; W1 then W2).
// 51 KB LDS -> 3 blocks/CU (12 waves/CU).

template <int NC2, bool AGG, bool RELU2>
__launch_bounds__(256, 3)
__global__ void fused_kernel(const float* __restrict__ h,
                             const int* __restrict__ row_ptr,
                             const int* __restrict__ esrc,
                             const float* __restrict__ W1,
                             const float* __restrict__ b1,
                             const float* __restrict__ W2,
                             const float* __restrict__ b2,
                             float* __restrict__ out, int M) {
    constexpr int K = 128;
    constexpr int MT = 64;
    constexpr int LDA = K + 8;
    __shared__ __align__(16) unsigned short As[MT][LDA];
    __shared__ __align__(16) unsigned short Wt[K][LDA];

    int tid = threadIdx.x;
    int wave = tid >> 6;
    int lane = tid & 63;
    int row0 = blockIdx.x * MT;

    // ---- Phase A: build A tile (bf16) in LDS ----
    if (AGG) {
        // z[i] = h[i] + sum_{e: dst=i} h[src_e]; one wave per node, 16 nodes/wave.
        const float2* h2 = (const float2*)h;
        for (int i = 0; i < 16; ++i) {
            int r = wave * 16 + i;
            int node = row0 + r;
            float2 acc = make_float2(0.f, 0.f);
            if (node < M) {
                acc = h2[(size_t)node * 64 + lane];
                int b = row_ptr[node], e = row_ptr[node + 1];
                int j = b;
                // 8-wide unroll: 8 independent gathers in flight per wave
                for (; j + 8 <= e; j += 8) {
                    int s0 = esrc[j + 0], s1 = esrc[j + 1];
                    int s2 = esrc[j + 2], s3 = esrc[j + 3];
                    int s4 = esrc[j + 4], s5 = esrc[j + 5];
                    int s6 = esrc[j + 6], s7 = esrc[j + 7];
                    float2 v0 = h2[(size_t)s0 * 64 + lane];
                    float2 v1 = h2[(size_t)s1 * 64 + lane];
                    float2 v2 = h2[(size_t)s2 * 64 + lane];
                    float2 v3 = h2[(size_t)s3 * 64 + lane];
                    float2 v4 = h2[(size_t)s4 * 64 + lane];
                    float2 v5 = h2[(size_t)s5 * 64 + lane];
                    float2 v6 = h2[(size_t)s6 * 64 + lane];
                    float2 v7 = h2[(size_t)s7 * 64 + lane];
                    acc.x += ((v0.x + v1.x) + (v2.x + v3.x)) +
                             ((v4.x + v5.x) + (v6.x + v7.x));
                    acc.y += ((v0.y + v1.y) + (v2.y + v3.y)) +
                             ((v4.y + v5.y) + (v6.y + v7.y));
                }
                for (; j + 2 <= e; j += 2) {
                    int s0 = esrc[j], s1 = esrc[j + 1];
                    float2 v0 = h2[(size_t)s0 * 64 + lane];
                    float2 v1 = h2[(size_t)s1 * 64 + lane];
                    acc.x += v0.x + v1.x;
                    acc.y += v0.y + v1.y;
                }
                for (; j < e; ++j) {
                    int s0 = esrc[j];
                    float2 v0 = h2[(size_t)s0 * 64 + lane];
                    acc.x += v0.x;
                    acc.y += v0.y;
                }
            }
            ushort2 bv;
            bv.x = f2bf(acc.x);
            bv.y = f2bf(acc.y);
            *(ushort2*)&As[r][lane * 2] = bv;
        }
    } else {
        for (int c = tid; c < MT * (K / 4); c += 256) {
            int r = c >> 5, ch = c & 31;
            float4 val = make_float4(0.f, 0.f, 0.f, 0.f);
            int grow = row0 + r;
            if (grow < M) val = *(const float4*)(h + (size_t)grow * K + ch * 4);
            ushort4 bv;
            bv.x = f2bf(val.x); bv.y = f2bf(val.y);
            bv.z = f2bf(val.z); bv.w = f2bf(val.w);
            *(ushort4*)(&As[r][ch * 4]) = bv;
        }
    }
    // stage W1 transposed: Wt[n][k] = bf16(W1[k*128 + n])
    for (int c = tid; c < K * K; c += 256) {
        int k = c >> 7, nn = c & 127;
        Wt[nn][k] = f2bf(W1[c]);
    }
    __syncthreads();

    int quad = lane >> 4;
    int l16 = lane & 15;
    int arow = wave * 16 + l16;

    // ---- GEMM1: Z = relu(A @ W1 + b1) ----
    bf16x8 af[4];
#pragma unroll
    for (int kt = 0; kt < 4; ++kt)
        af[kt] = *(const bf16x8*)(&As[arow][kt * 32 + quad * 8]);

    f32x4 racc[8];
#pragma unroll
    for (int nt = 0; nt < 8; ++nt) {
        int ncol = nt * 16 + l16;
        f32x4 acc = {0.f, 0.f, 0.f, 0.f};
#pragma unroll
        for (int kt = 0; kt < 4; ++kt) {
            bf16x8 bfr = *(const bf16x8*)(&Wt[ncol][kt * 32 + quad * 8]);
            acc = __builtin_amdgcn_mfma_f32_16x16x32_bf16(af[kt], bfr, acc, 0, 0, 0);
        }
        racc[nt] = acc;
    }

    // Write Z into As (own 16-row band only -> no cross-wave hazard)
#pragma unroll
    for (int nt = 0; nt < 8; ++nt) {
        int ncol = nt * 16 + l16;
        float bs = b1[ncol];
#pragma unroll
        for (int r = 0; r < 4; ++r) {
            float v = racc[nt][r] + bs;
            if (v < 0.f) v = 0.f;
            As[wave * 16 + quad * 4 + r][ncol] = f2bf(v);
        }
    }
    __syncthreads();  // all waves done reading W1t + writing Z

    // stage W2 transposed (overwrites W1t)
    for (int c = tid; c < K * NC2; c += 256) {
        int k = c / NC2, nn = c % NC2;
        Wt[nn][k] = f2bf(W2[c]);
    }
    __syncthreads();

    // ---- GEMM2: out = act(Z @ W2 + b2) ----
    bf16x8 zf[4];
#pragma unroll
    for (int kt = 0; kt < 4; ++kt)
        zf[kt] = *(const bf16x8*)(&As[arow][kt * 32 + quad * 8]);

    constexpr int NT2 = NC2 / 16;
#pragma unroll
    for (int nt = 0; nt < NT2; ++nt) {
        int ncol = nt * 16 + l16;
        f32x4 acc = {0.f, 0.f, 0.f, 0.f};
#pragma unroll
        for (int kt = 0; kt < 4; ++kt) {
            bf16x8 bfr = *(const bf16x8*)(&Wt[ncol][kt * 32 + quad * 8]);
            acc = __builtin_amdgcn_mfma_f32_16x16x32_bf16(zf[kt], bfr, acc, 0, 0, 0);
        }
        float bs = b2[ncol];
#pragma unroll
        for (int r = 0; r < 4; ++r) {
            int grow = row0 + wave * 16 + quad * 4 + r;
            if (grow < M) {
                float v = acc[r] + bs;
                if (RELU2 && v < 0.f) v = 0.f;
                out[(size_t)grow * NC2 + ncol] = v;
            }
        }
    }
}

// ---------------- launch ----------------

extern "C" void kernel_launch(void* const* d_in, const int* in_sizes, int n_in,
                              void* d_out, int out_size, void* d_ws, size_t ws_size,
                              hipStream_t stream) {
    const float* x = (const float*)d_in[0];
    const int* ei = (const int*)d_in[1];
    int N = in_sizes[0] / DH;
    int E = in_sizes[1] / 2;
    const int* src = ei;
    const int* dstv = ei + E;

    char* ws = (char*)d_ws;
    size_t off = 0;
    auto alloc = [&](size_t bytes) -> void* {
        void* p = ws + off;
        off += (bytes + 255) & ~(size_t)255;
        return p;
    };
    float* hA = (float*)alloc((size_t)N * DH * 4);
    float* hB = (float*)alloc((size_t)N * DH * 4);
    int* cnt     = (int*)alloc((size_t)N * 4);
    int* row_ptr = (int*)alloc((size_t)(N + 1) * 4);
    int* cursor  = (int*)alloc((size_t)N * 4);
    int* bsum    = (int*)alloc(256 * 4);
    int* esrc    = (int*)alloc((size_t)E * 4);

    int nb = (N + 255) / 256;
    int eb = (E + 255) / 256;
    zero_i32<<<nb, 256, 0, stream>>>(cnt, N);
    hist_kernel<<<eb, 256, 0, stream>>>(dstv, cnt, E, N);
    scan1_kernel<<<nb, 256, 0, stream>>>(cnt, row_ptr, bsum, N);
    scan2_kernel<<<1, 256, 0, stream>>>(bsum, nb);
    scan3_kernel<<<nb, 256, 0, stream>>>(row_ptr, bsum, cursor, N, E);
    fill_kernel<<<eb, 256, 0, stream>>>(src, dstv, cursor, esrc, E, N);

    int gb = (N + 63) / 64;

    const float* c1w1 = (const float*)d_in[2];
    const float* c1b1 = (const float*)d_in[3];
    const float* c1w2 = (const float*)d_in[4];
    const float* c1b2 = (const float*)d_in[5];
    const float* c2w1 = (const float*)d_in[6];
    const float* c2b1 = (const float*)d_in[7];
    const float* c2w2 = (const float*)d_in[8];
    const float* c2b2 = (const float*)d_in[9];
    const float* c3w1 = (const float*)d_in[10];
    const float* c3b1 = (const float*)d_in[11];
    const float* c3w2 = (const float*)d_in[12];
    const float* c3b2 = (const float*)d_in[13];
    const float* l1w  = (const float*)d_in[14];
    const float* l1b  = (const float*)d_in[15];
    const float* l2w  = (const float*)d_in[16];
    const float* l2b  = (const float*)d_in[17];

    // conv1: agg(x) -> MLP -> hA
    fused_kernel<128, true, true><<<gb, 256, 0, stream>>>(
        x, row_ptr, esrc, c1w1, c1b1, c1w2, c1b2, hA, N);
    // conv2: agg(hA) -> MLP -> hB
    fused_kernel<128, true, true><<<gb, 256, 0, stream>>>(
        hA, row_ptr, esrc, c2w1, c2b1, c2w2, c2b2, hB, N);
    // conv3: agg(hB) -> MLP -> hA
    fused_kernel<128, true, true><<<gb, 256, 0, stream>>>(
        hB, row_ptr, esrc, c3w1, c3b1, c3w2, c3b2, hA, N);
    // head: relu(hA@l1+b1) @ l2 + b2 -> d_out
    fused_kernel<64, false, false><<<gb, 256, 0, stream>>>(
        hA, row_ptr, esrc, l1w, l1b, l2w, l2b, (float*)d_out, N);
}

// Round 4
// 466.944 us; speedup vs baseline: 1.3480x; 1.2417x over previous
//
#include <hip/hip_runtime.h>
#include <hip/hip_bf16.h>

typedef __attribute__((ext_vector_type(8))) short bf16x8;
typedef __attribute__((ext_vector_type(4))) float f32x4;

#define DH 128
#define DOUT 64

static __device__ __forceinline__ unsigned short f2bf(float f) {
    __hip_bfloat16 h = __float2bfloat16(f);
    return *(unsigned short*)&h;
}
static __device__ __forceinline__ float2 bfp2f(unsigned int u) {
    float2 r;
    r.x = __uint_as_float(u << 16);
    r.y = __uint_as_float(u & 0xffff0000u);
    return r;
}

// ---------------- prep: x -> bf16 ----------------

__global__ void cvt_kernel(const float* __restrict__ x, unsigned short* __restrict__ y,
                           int n4) {
    int i = blockIdx.x * blockDim.x + threadIdx.x;
    if (i < n4) {
        float4 v = ((const float4*)x)[i];
        ushort4 b;
        b.x = f2bf(v.x); b.y = f2bf(v.y); b.z = f2bf(v.z); b.w = f2bf(v.w);
        ((ushort4*)y)[i] = b;
    }
}

// ---------------- prep: weights -> bf16, transposed [n][k] ----------------
// matrices 0..6: 128x128; matrix 7: 128x64.

struct WPrep {
    const float* src[8];
    unsigned short* dst[8];
};

__global__ void wprep_kernel(WPrep p) {
    int id = blockIdx.x * blockDim.x + threadIdx.x;
    int m, off;
    if (id < 7 * 16384) { m = id >> 14; off = id & 16383; }
    else {
        m = 7; off = id - 7 * 16384;
        if (off >= 8192) return;
    }
    int shift = (m == 7) ? 6 : 7;
    int nc = 1 << shift;
    int k = off >> shift;
    int n = off & (nc - 1);
    p.dst[m][n * 128 + k] = f2bf(p.src[m][off]);
}

// ---------------- CSR build ----------------

__global__ void zero_i32(int* __restrict__ p, int n) {
    int i = blockIdx.x * blockDim.x + threadIdx.x;
    if (i < n) p[i] = 0;
}

__global__ void hist_kernel(const int* __restrict__ dst, int* __restrict__ cnt,
                            int E, int n) {
    int e = blockIdx.x * blockDim.x + threadIdx.x;
    if (e < E) {
        int d = dst[e];
        if ((unsigned)d < (unsigned)n) atomicAdd(&cnt[d], 1);
    }
}

__global__ void scan1_kernel(const int* __restrict__ cnt, int* __restrict__ row_ptr,
                             int* __restrict__ bsum, int n) {
    __shared__ int s[256];
    int tid = threadIdx.x;
    int i = blockIdx.x * 256 + tid;
    int v = (i < n) ? cnt[i] : 0;
    s[tid] = v;
    __syncthreads();
    for (int off = 1; off < 256; off <<= 1) {
        int t = (tid >= off) ? s[tid - off] : 0;
        __syncthreads();
        s[tid] += t;
        __syncthreads();
    }
    if (i < n) row_ptr[i] = s[tid] - v;
    if (tid == 255) bsum[blockIdx.x] = s[255];
}

__global__ void scan2_kernel(int* __restrict__ bsum, int nb) {
    __shared__ int s[256];
    int tid = threadIdx.x;
    int v = (tid < nb) ? bsum[tid] : 0;
    s[tid] = v;
    __syncthreads();
    for (int off = 1; off < 256; off <<= 1) {
        int t = (tid >= off) ? s[tid - off] : 0;
        __syncthreads();
        s[tid] += t;
        __syncthreads();
    }
    if (tid < nb) bsum[tid] = s[tid] - v;
}

__global__ void scan3_kernel(int* __restrict__ row_ptr, const int* __restrict__ bsum,
                             int* __restrict__ cursor, int n, int E) {
    int i = blockIdx.x * 256 + threadIdx.x;
    if (i < n) {
        int v = row_ptr[i] + bsum[blockIdx.x];
        row_ptr[i] = v;
        cursor[i] = v;
    }
    if (i == 0) row_ptr[n] = E;
}

__global__ void fill_kernel(const int* __restrict__ src, const int* __restrict__ dst,
                            int* __restrict__ cursor, int* __restrict__ esrc,
                            int E, int n) {
    int e = blockIdx.x * blockDim.x + threadIdx.x;
    if (e < E) {
        int d = dst[e];
        if ((unsigned)d < (unsigned)n) {
            int p = atomicAdd(&cursor[d], 1);
            esrc[p] = src[e];
        }
    }
}

// ---------------- fused layer: [agg] -> GEMM1(relu) -> GEMM2(opt relu) ----------------
// h is bf16 [M,128]. W1t/W2t are bf16 transposed [n][k] in global (L1-resident;
// B-fragments loaded straight into registers -> no Wt LDS, no transpose staging).
// Each wave owns a 16-row LDS band (agg output + Z round-trip) -> NO __syncthreads.
// LDS = 17.4 KB -> occupancy VGPR-limited, not LDS-limited.

template <bool AGG, int NC2, bool OUT_BF16, bool RELU2>
__launch_bounds__(256, 4)
__global__ void layer_kernel(const unsigned short* __restrict__ h,
                             const int* __restrict__ row_ptr,
                             const int* __restrict__ esrc,
                             const unsigned short* __restrict__ W1t,
                             const float* __restrict__ b1,
                             const unsigned short* __restrict__ W2t,
                             const float* __restrict__ b2,
                             void* __restrict__ outp, int M) {
    constexpr int K = 128;
    constexpr int MT = 64;
    constexpr int LDA = K + 8;
    __shared__ __align__(16) unsigned short As[MT][LDA];

    int tid = threadIdx.x;
    int wave = tid >> 6;
    int lane = tid & 63;
    int row0 = blockIdx.x * MT;

    const unsigned int* h2 = (const unsigned int*)h;  // bf16 pair per uint

    // ---- Phase A: build this wave's 16-row band of A (bf16) in LDS ----
    for (int i = 0; i < 16; ++i) {
        int r = wave * 16 + i;
        int node = row0 + r;
        float2 acc = make_float2(0.f, 0.f);
        if (node < M) {
            acc = bfp2f(h2[(size_t)node * 64 + lane]);
            if (AGG) {
                int b = row_ptr[node], e = row_ptr[node + 1];
                int j = b;
                for (; j + 8 <= e; j += 8) {
                    unsigned int v0 = h2[(size_t)esrc[j + 0] * 64 + lane];
                    unsigned int v1 = h2[(size_t)esrc[j + 1] * 64 + lane];
                    unsigned int v2 = h2[(size_t)esrc[j + 2] * 64 + lane];
                    unsigned int v3 = h2[(size_t)esrc[j + 3] * 64 + lane];
                    unsigned int v4 = h2[(size_t)esrc[j + 4] * 64 + lane];
                    unsigned int v5 = h2[(size_t)esrc[j + 5] * 64 + lane];
                    unsigned int v6 = h2[(size_t)esrc[j + 6] * 64 + lane];
                    unsigned int v7 = h2[(size_t)esrc[j + 7] * 64 + lane];
                    float2 f0 = bfp2f(v0), f1 = bfp2f(v1), f2 = bfp2f(v2), f3 = bfp2f(v3);
                    float2 f4 = bfp2f(v4), f5 = bfp2f(v5), f6 = bfp2f(v6), f7 = bfp2f(v7);
                    acc.x += ((f0.x + f1.x) + (f2.x + f3.x)) +
                             ((f4.x + f5.x) + (f6.x + f7.x));
                    acc.y += ((f0.y + f1.y) + (f2.y + f3.y)) +
                             ((f4.y + f5.y) + (f6.y + f7.y));
                }
                for (; j + 2 <= e; j += 2) {
                    unsigned int v0 = h2[(size_t)esrc[j] * 64 + lane];
                    unsigned int v1 = h2[(size_t)esrc[j + 1] * 64 + lane];
                    float2 f0 = bfp2f(v0), f1 = bfp2f(v1);
                    acc.x += f0.x + f1.x;
                    acc.y += f0.y + f1.y;
                }
                for (; j < e; ++j) {
                    float2 f0 = bfp2f(h2[(size_t)esrc[j] * 64 + lane]);
                    acc.x += f0.x;
                    acc.y += f0.y;
                }
            }
        }
        unsigned int pv = (unsigned int)f2bf(acc.x) | ((unsigned int)f2bf(acc.y) << 16);
        *(unsigned int*)&As[r][lane * 2] = pv;
    }

    // wave-local: ensure LDS writes visible before cross-lane reads (same wave)
    asm volatile("s_waitcnt lgkmcnt(0)" ::: "memory");

    int quad = lane >> 4;
    int l16 = lane & 15;
    int arow = wave * 16 + l16;

    // ---- GEMM1: Z = relu(A @ W1 + b1), B-fragments straight from global ----
    bf16x8 af[4];
#pragma unroll
    for (int kt = 0; kt < 4; ++kt)
        af[kt] = *(const bf16x8*)(&As[arow][kt * 32 + quad * 8]);

    f32x4 racc[8];
#pragma unroll
    for (int nt = 0; nt < 8; ++nt) {
        int ncol = nt * 16 + l16;
        const unsigned short* wp = W1t + ncol * 128 + quad * 8;
        f32x4 acc = {0.f, 0.f, 0.f, 0.f};
#pragma unroll
        for (int kt = 0; kt < 4; ++kt) {
            bf16x8 bfr = *(const bf16x8*)(wp + kt * 32);
            acc = __builtin_amdgcn_mfma_f32_16x16x32_bf16(af[kt], bfr, acc, 0, 0, 0);
        }
        racc[nt] = acc;
    }

    // write Z into own band (C-layout rows: wave*16 + quad*4 + r)
#pragma unroll
    for (int nt = 0; nt < 8; ++nt) {
        int ncol = nt * 16 + l16;
        float bs = b1[ncol];
#pragma unroll
        for (int r = 0; r < 4; ++r) {
            float v = racc[nt][r] + bs;
            if (v < 0.f) v = 0.f;
            As[wave * 16 + quad * 4 + r][ncol] = f2bf(v);
        }
    }

    asm volatile("s_waitcnt lgkmcnt(0)" ::: "memory");

    // ---- GEMM2: out = act(Z @ W2 + b2) ----
    bf16x8 zf[4];
#pragma unroll
    for (int kt = 0; kt < 4; ++kt)
        zf[kt] = *(const bf16x8*)(&As[arow][kt * 32 + quad * 8]);

    constexpr int NT2 = NC2 / 16;
#pragma unroll
    for (int nt = 0; nt < NT2; ++nt) {
        int ncol = nt * 16 + l16;
        const unsigned short* wp = W2t + ncol * 128 + quad * 8;
        f32x4 acc = {0.f, 0.f, 0.f, 0.f};
#pragma unroll
        for (int kt = 0; kt < 4; ++kt) {
            bf16x8 bfr = *(const bf16x8*)(wp + kt * 32);
            acc = __builtin_amdgcn_mfma_f32_16x16x32_bf16(zf[kt], bfr, acc, 0, 0, 0);
        }
        float bs = b2[ncol];
#pragma unroll
        for (int r = 0; r < 4; ++r) {
            int grow = row0 + wave * 16 + quad * 4 + r;
            if (grow < M) {
                float v = acc[r] + bs;
                if (RELU2 && v < 0.f) v = 0.f;
                if (OUT_BF16)
                    ((unsigned short*)outp)[(size_t)grow * NC2 + ncol] = f2bf(v);
                else
                    ((float*)outp)[(size_t)grow * NC2 + ncol] = v;
            }
        }
    }
}

// ---------------- launch ----------------

extern "C" void kernel_launch(void* const* d_in, const int* in_sizes, int n_in,
                              void* d_out, int out_size, void* d_ws, size_t ws_size,
                              hipStream_t stream) {
    const float* x = (const float*)d_in[0];
    const int* ei = (const int*)d_in[1];
    int N = in_sizes[0] / DH;
    int E = in_sizes[1] / 2;
    const int* src = ei;
    const int* dstv = ei + E;

    char* ws = (char*)d_ws;
    size_t off = 0;
    auto alloc = [&](size_t bytes) -> void* {
        void* p = ws + off;
        off += (bytes + 255) & ~(size_t)255;
        return p;
    };
    unsigned short* xb = (unsigned short*)alloc((size_t)N * DH * 2);
    unsigned short* hA = (unsigned short*)alloc((size_t)N * DH * 2);
    unsigned short* hB = (unsigned short*)alloc((size_t)N * DH * 2);
    unsigned short* wt[8];
    for (int m = 0; m < 8; ++m) wt[m] = (unsigned short*)alloc(16384 * 2);
    int* cnt     = (int*)alloc((size_t)N * 4);
    int* row_ptr = (int*)alloc((size_t)(N + 1) * 4);
    int* cursor  = (int*)alloc((size_t)N * 4);
    int* bsum    = (int*)alloc(256 * 4);
    int* esrc    = (int*)alloc((size_t)E * 4);

    // weight prep (bf16 + transpose)
    WPrep wp;
    wp.src[0] = (const float*)d_in[2];   // c1_w1
    wp.src[1] = (const float*)d_in[4];   // c1_w2
    wp.src[2] = (const float*)d_in[6];   // c2_w1
    wp.src[3] = (const float*)d_in[8];   // c2_w2
    wp.src[4] = (const float*)d_in[10];  // c3_w1
    wp.src[5] = (const float*)d_in[12];  // c3_w2
    wp.src[6] = (const float*)d_in[14];  // lin1_w
    wp.src[7] = (const float*)d_in[16];  // lin2_w (128x64)
    for (int m = 0; m < 8; ++m) wp.dst[m] = wt[m];
    wprep_kernel<<<(7 * 16384 + 8192 + 255) / 256, 256, 0, stream>>>(wp);

    int n4 = N * DH / 4;
    cvt_kernel<<<(n4 + 255) / 256, 256, 0, stream>>>(x, xb, n4);

    int nb = (N + 255) / 256;
    int eb = (E + 255) / 256;
    zero_i32<<<nb, 256, 0, stream>>>(cnt, N);
    hist_kernel<<<eb, 256, 0, stream>>>(dstv, cnt, E, N);
    scan1_kernel<<<nb, 256, 0, stream>>>(cnt, row_ptr, bsum, N);
    scan2_kernel<<<1, 256, 0, stream>>>(bsum, nb);
    scan3_kernel<<<nb, 256, 0, stream>>>(row_ptr, bsum, cursor, N, E);
    fill_kernel<<<eb, 256, 0, stream>>>(src, dstv, cursor, esrc, E, N);

    int gb = (N + 63) / 64;

    const float* c1b1 = (const float*)d_in[3];
    const float* c1b2 = (const float*)d_in[5];
    const float* c2b1 = (const float*)d_in[7];
    const float* c2b2 = (const float*)d_in[9];
    const float* c3b1 = (const float*)d_in[11];
    const float* c3b2 = (const float*)d_in[13];
    const float* l1b  = (const float*)d_in[15];
    const float* l2b  = (const float*)d_in[17];

    // conv1: agg(xb) -> MLP -> hA (bf16)
    layer_kernel<true, 128, true, true><<<gb, 256, 0, stream>>>(
        xb, row_ptr, esrc, wt[0], c1b1, wt[1], c1b2, hA, N);
    // conv2
    layer_kernel<true, 128, true, true><<<gb, 256, 0, stream>>>(
        hA, row_ptr, esrc, wt[2], c2b1, wt[3], c2b2, hB, N);
    // conv3
    layer_kernel<true, 128, true, true><<<gb, 256, 0, stream>>>(
        hB, row_ptr, esrc, wt[4], c3b1, wt[5], c3b2, hA, N);
    // head: relu(hA@l1+b1)@l2+b2 -> fp32 d_out
    layer_kernel<false, 64, false, false><<<gb, 256, 0, stream>>>(
        hA, row_ptr, esrc, wt[6], l1b, wt[7], l2b, d_out, N);
}

// Round 5
// 343.500 us; speedup vs baseline: 1.8325x; 1.3594x over previous
//
#include <hip/hip_runtime.h>
#include <hip/hip_bf16.h>

typedef __attribute__((ext_vector_type(8))) short bf16x8;
typedef __attribute__((ext_vector_type(4))) float f32x4;

#define DH 128
#define DOUT 64

static __device__ __forceinline__ unsigned short f2bf(float f) {
    __hip_bfloat16 h = __float2bfloat16(f);
    return *(unsigned short*)&h;
}
static __device__ __forceinline__ float2 bfp2f(unsigned int u) {
    float2 r;
    r.x = __uint_as_float(u << 16);
    r.y = __uint_as_float(u & 0xffff0000u);
    return r;
}

// ---------------- prep: x -> bf16  +  weights -> bf16 transposed [n][k] ----------------

struct WPrep {
    const float* src[8];
    unsigned short* dst[8];
};

__global__ void prep_kernel(const float* __restrict__ x, unsigned short* __restrict__ xb,
                            int n4, WPrep p) {
    int id = blockIdx.x * blockDim.x + threadIdx.x;
    if (id < n4) {
        float4 v = ((const float4*)x)[id];
        ushort4 b;
        b.x = f2bf(v.x); b.y = f2bf(v.y); b.z = f2bf(v.z); b.w = f2bf(v.w);
        ((ushort4*)xb)[id] = b;
        return;
    }
    id -= n4;
    int m, off;
    if (id < 7 * 16384) { m = id >> 14; off = id & 16383; }
    else {
        m = 7; off = id - 7 * 16384;
        if (off >= 8192) return;
    }
    int shift = (m == 7) ? 6 : 7;
    int nc = 1 << shift;
    int k = off >> shift;
    int n = off & (nc - 1);
    p.dst[m][n * 128 + k] = f2bf(p.src[m][off]);
}

// ---------------- CSR build ----------------

__global__ void zero_i32(int* __restrict__ p, int n) {
    int i = blockIdx.x * blockDim.x + threadIdx.x;
    if (i < n) p[i] = 0;
}

// histogram + record per-edge rank within its dst bucket
__global__ void hist_kernel(const int* __restrict__ dst, int* __restrict__ cnt,
                            int* __restrict__ rank, int E, int n) {
    int e = blockIdx.x * blockDim.x + threadIdx.x;
    if (e < E) {
        int d = dst[e];
        if ((unsigned)d < (unsigned)n) rank[e] = atomicAdd(&cnt[d], 1);
    }
}

__global__ void scan1_kernel(const int* __restrict__ cnt, int* __restrict__ row_ptr,
                             int* __restrict__ bsum, int n) {
    __shared__ int s[256];
    int tid = threadIdx.x;
    int i = blockIdx.x * 256 + tid;
    int v = (i < n) ? cnt[i] : 0;
    s[tid] = v;
    __syncthreads();
    for (int off = 1; off < 256; off <<= 1) {
        int t = (tid >= off) ? s[tid - off] : 0;
        __syncthreads();
        s[tid] += t;
        __syncthreads();
    }
    if (i < n) row_ptr[i] = s[tid] - v;
    if (tid == 255) bsum[blockIdx.x] = s[255];
}

__global__ void scan2_kernel(int* __restrict__ bsum, int nb) {
    __shared__ int s[256];
    int tid = threadIdx.x;
    int v = (tid < nb) ? bsum[tid] : 0;
    s[tid] = v;
    __syncthreads();
    for (int off = 1; off < 256; off <<= 1) {
        int t = (tid >= off) ? s[tid - off] : 0;
        __syncthreads();
        s[tid] += t;
        __syncthreads();
    }
    if (tid < nb) bsum[tid] = s[tid] - v;
}

__global__ void scan3_kernel(int* __restrict__ row_ptr, const int* __restrict__ bsum,
                             int n, int E) {
    int i = blockIdx.x * 256 + threadIdx.x;
    if (i < n) row_ptr[i] += bsum[blockIdx.x];
    if (i == 0) row_ptr[n] = E;
}

// atomic-free fill: position = row_ptr[dst] + rank. Stores src*64 (pre-scaled
// uint offset into the [M,128]-bf16 feature array viewed as uint pairs).
__global__ void fill_kernel(const int* __restrict__ src, const int* __restrict__ dst,
                            const int* __restrict__ row_ptr, const int* __restrict__ rank,
                            int* __restrict__ esrc, int E, int n) {
    int e = blockIdx.x * blockDim.x + threadIdx.x;
    if (e < E) {
        int d = dst[e];
        if ((unsigned)d < (unsigned)n)
            esrc[row_ptr[d] + rank[e]] = src[e] * 64;
    }
}

// ---------------- fused layer: [agg] -> GEMM1(relu) -> GEMM2(opt relu) ----------------
// 16-row M tile, 256 threads (4 waves) -> grid = N/16 = 3125 blocks.
// LDS: As[16][136] + Zs[16][136] = 8.7 KB -> occupancy capped by VGPR only.
// Weights read transposed-bf16 straight from global (L1/L2-resident).

template <bool AGG, int NC2, bool OUT_BF16, bool RELU2>
__launch_bounds__(256, 8)
__global__ void layer_kernel(const unsigned short* __restrict__ h,
                             const int* __restrict__ row_ptr,
                             const int* __restrict__ esrc,
                             const unsigned short* __restrict__ W1t,
                             const float* __restrict__ b1,
                             const unsigned short* __restrict__ W2t,
                             const float* __restrict__ b2,
                             void* __restrict__ outp, int M) {
    constexpr int LDA = 128 + 8;
    __shared__ __align__(16) unsigned short As[16][LDA];
    __shared__ __align__(16) unsigned short Zs[16][LDA];

    int tid = threadIdx.x;
    int wave = __builtin_amdgcn_readfirstlane(tid >> 6);  // wave-uniform
    int lane = tid & 63;
    int row0 = blockIdx.x * 16;

    const unsigned int* hb = (const unsigned int*)h + lane;  // + node*64 indexes row

    // ---- Phase A: build A tile (bf16) in LDS; wave handles 4 rows ----
    if (AGG) {
        for (int i = 0; i < 4; ++i) {
            int r = wave * 4 + i;
            int node = row0 + r;
            float2 acc = make_float2(0.f, 0.f);
            if (node < M) {
                acc = bfp2f(hb[node * 64]);
                int b = row_ptr[node], e = row_ptr[node + 1];
                int j = b;
                for (; j + 8 <= e; j += 8) {
                    unsigned int v0 = hb[esrc[j + 0]];
                    unsigned int v1 = hb[esrc[j + 1]];
                    unsigned int v2 = hb[esrc[j + 2]];
                    unsigned int v3 = hb[esrc[j + 3]];
                    unsigned int v4 = hb[esrc[j + 4]];
                    unsigned int v5 = hb[esrc[j + 5]];
                    unsigned int v6 = hb[esrc[j + 6]];
                    unsigned int v7 = hb[esrc[j + 7]];
                    float2 f0 = bfp2f(v0), f1 = bfp2f(v1), f2 = bfp2f(v2), f3 = bfp2f(v3);
                    float2 f4 = bfp2f(v4), f5 = bfp2f(v5), f6 = bfp2f(v6), f7 = bfp2f(v7);
                    acc.x += ((f0.x + f1.x) + (f2.x + f3.x)) +
                             ((f4.x + f5.x) + (f6.x + f7.x));
                    acc.y += ((f0.y + f1.y) + (f2.y + f3.y)) +
                             ((f4.y + f5.y) + (f6.y + f7.y));
                }
                for (; j + 2 <= e; j += 2) {
                    unsigned int v0 = hb[esrc[j]];
                    unsigned int v1 = hb[esrc[j + 1]];
                    float2 f0 = bfp2f(v0), f1 = bfp2f(v1);
                    acc.x += f0.x + f1.x;
                    acc.y += f0.y + f1.y;
                }
                for (; j < e; ++j) {
                    float2 f0 = bfp2f(hb[esrc[j]]);
                    acc.x += f0.x;
                    acc.y += f0.y;
                }
            }
            unsigned int pv = (unsigned int)f2bf(acc.x) | ((unsigned int)f2bf(acc.y) << 16);
            *(unsigned int*)&As[r][lane * 2] = pv;
        }
    } else {
        // stage 16x128 bf16 tile: one 16B load per thread
        int r = tid >> 4, ch = tid & 15;
        int grow = row0 + r;
        bf16x8 v = {};
        if (grow < M) v = *(const bf16x8*)(h + (size_t)grow * 128 + ch * 8);
        *(bf16x8*)(&As[r][ch * 8]) = v;
    }
    __syncthreads();

    int quad = lane >> 4;
    int l16 = lane & 15;

    // ---- GEMM1: Z = relu(A @ W1 + b1); wave computes cols [wave*32, wave*32+32) ----
    bf16x8 af[4];
#pragma unroll
    for (int kt = 0; kt < 4; ++kt)
        af[kt] = *(const bf16x8*)(&As[l16][kt * 32 + quad * 8]);

#pragma unroll
    for (int p = 0; p < 2; ++p) {
        int ncol = (wave * 2 + p) * 16 + l16;
        const unsigned short* wp = W1t + ncol * 128 + quad * 8;
        f32x4 acc = {0.f, 0.f, 0.f, 0.f};
#pragma unroll
        for (int kt = 0; kt < 4; ++kt) {
            bf16x8 bfr = *(const bf16x8*)(wp + kt * 32);
            acc = __builtin_amdgcn_mfma_f32_16x16x32_bf16(af[kt], bfr, acc, 0, 0, 0);
        }
        float bs = b1[ncol];
#pragma unroll
        for (int r = 0; r < 4; ++r) {
            float v = acc[r] + bs;
            if (v < 0.f) v = 0.f;
            Zs[quad * 4 + r][ncol] = f2bf(v);
        }
    }
    __syncthreads();

    // ---- GEMM2: out = act(Z @ W2 + b2) ----
    bf16x8 zf[4];
#pragma unroll
    for (int kt = 0; kt < 4; ++kt)
        zf[kt] = *(const bf16x8*)(&Zs[l16][kt * 32 + quad * 8]);

    constexpr int PT2 = NC2 / 64;  // n-tiles per wave (2 for 128, 1 for 64)
#pragma unroll
    for (int p = 0; p < PT2; ++p) {
        int ncol = (wave * PT2 + p) * 16 + l16;
        const unsigned short* wp = W2t + ncol * 128 + quad * 8;
        f32x4 acc = {0.f, 0.f, 0.f, 0.f};
#pragma unroll
        for (int kt = 0; kt < 4; ++kt) {
            bf16x8 bfr = *(const bf16x8*)(wp + kt * 32);
            acc = __builtin_amdgcn_mfma_f32_16x16x32_bf16(zf[kt], bfr, acc, 0, 0, 0);
        }
        float bs = b2[ncol];
#pragma unroll
        for (int r = 0; r < 4; ++r) {
            int grow = row0 + quad * 4 + r;
            if (grow < M) {
                float v = acc[r] + bs;
                if (RELU2 && v < 0.f) v = 0.f;
                if (OUT_BF16)
                    ((unsigned short*)outp)[(size_t)grow * NC2 + ncol] = f2bf(v);
                else
                    ((float*)outp)[(size_t)grow * NC2 + ncol] = v;
            }
        }
    }
}

// ---------------- launch ----------------

extern "C" void kernel_launch(void* const* d_in, const int* in_sizes, int n_in,
                              void* d_out, int out_size, void* d_ws, size_t ws_size,
                              hipStream_t stream) {
    const float* x = (const float*)d_in[0];
    const int* ei = (const int*)d_in[1];
    int N = in_sizes[0] / DH;
    int E = in_sizes[1] / 2;
    const int* src = ei;
    const int* dstv = ei + E;

    char* ws = (char*)d_ws;
    size_t off = 0;
    auto alloc = [&](size_t bytes) -> void* {
        void* p = ws + off;
        off += (bytes + 255) & ~(size_t)255;
        return p;
    };
    unsigned short* xb = (unsigned short*)alloc((size_t)N * DH * 2);
    unsigned short* hA = (unsigned short*)alloc((size_t)N * DH * 2);
    unsigned short* hB = (unsigned short*)alloc((size_t)N * DH * 2);
    unsigned short* wt[8];
    for (int m = 0; m < 8; ++m) wt[m] = (unsigned short*)alloc(16384 * 2);
    int* cnt     = (int*)alloc((size_t)N * 4);
    int* row_ptr = (int*)alloc((size_t)(N + 1) * 4);
    int* rank    = (int*)alloc((size_t)E * 4);
    int* bsum    = (int*)alloc(256 * 4);
    int* esrc    = (int*)alloc((size_t)E * 4);

    // prep: x->bf16 and weights->bf16 transposed
    WPrep wp;
    wp.src[0] = (const float*)d_in[2];
    wp.src[1] = (const float*)d_in[4];
    wp.src[2] = (const float*)d_in[6];
    wp.src[3] = (const float*)d_in[8];
    wp.src[4] = (const float*)d_in[10];
    wp.src[5] = (const float*)d_in[12];
    wp.src[6] = (const float*)d_in[14];
    wp.src[7] = (const float*)d_in[16];
    for (int m = 0; m < 8; ++m) wp.dst[m] = wt[m];
    int n4 = N * DH / 4;
    prep_kernel<<<(n4 + 7 * 16384 + 8192 + 255) / 256, 256, 0, stream>>>(x, xb, n4, wp);

    int nb = (N + 255) / 256;
    int eb = (E + 255) / 256;
    zero_i32<<<nb, 256, 0, stream>>>(cnt, N);
    hist_kernel<<<eb, 256, 0, stream>>>(dstv, cnt, rank, E, N);
    scan1_kernel<<<nb, 256, 0, stream>>>(cnt, row_ptr, bsum, N);
    scan2_kernel<<<1, 256, 0, stream>>>(bsum, nb);
    scan3_kernel<<<nb, 256, 0, stream>>>(row_ptr, bsum, N, E);
    fill_kernel<<<eb, 256, 0, stream>>>(src, dstv, row_ptr, rank, esrc, E, N);

    int gb = (N + 15) / 16;

    const float* c1b1 = (const float*)d_in[3];
    const float* c1b2 = (const float*)d_in[5];
    const float* c2b1 = (const float*)d_in[7];
    const float* c2b2 = (const float*)d_in[9];
    const float* c3b1 = (const float*)d_in[11];
    const float* c3b2 = (const float*)d_in[13];
    const float* l1b  = (const float*)d_in[15];
    const float* l2b  = (const float*)d_in[17];

    layer_kernel<true, 128, true, true><<<gb, 256, 0, stream>>>(
        xb, row_ptr, esrc, wt[0], c1b1, wt[1], c1b2, hA, N);
    layer_kernel<true, 128, true, true><<<gb, 256, 0, stream>>>(
        hA, row_ptr, esrc, wt[2], c2b1, wt[3], c2b2, hB, N);
    layer_kernel<true, 128, true, true><<<gb, 256, 0, stream>>>(
        hB, row_ptr, esrc, wt[4], c3b1, wt[5], c3b2, hA, N);
    layer_kernel<false, 64, false, false><<<gb, 256, 0, stream>>>(
        hA, row_ptr, esrc, wt[6], l1b, wt[7], l2b, d_out, N);
}